// Round 5
// baseline (353.136 us; speedup 1.0000x reference)
//
#include <hip/hip_runtime.h>

// Retrace loss, restructured to remove ALL serial dependence from the
// memory-streaming pass.
//
// Per 256-element chunk, with per-element suffix composites C[t]=(A,B) s.t.
// y[t] = C.A*y_in + C.B (y_in = state entering the chunk from above), the
// chunk's loss contribution collapses to  s2 - 2*y_in*s1 + y_in^2*s0  with
// s0 = sum C.A^2, s1 = sum P*C.A, s2 = sum P^2, P = Q - C.B.  So kernel A
// emits just 5 scalars per chunk (A_c, B_c, s0, s1, s2) and is a pure
// streaming kernel: ascending lane addresses, ascending chunk walk, zero
// loop-carried dependence, register double-buffer. Kernel B resolves the
// sequential recurrence: 16 scalar steps per row over 1.3 MB of workspace.
// (R1-R4 all plateaued at ~3 TB/s delivered; the shared features were a
// serial chain against memory and descending addressing — both removed.)

#define NROWS 4096
#define TLEN  4096
#define CHUNK 256                  // 64 lanes x 4 elements
#define CPR   (TLEN / CHUNK)       // 16 chunks per row
#define BLOCK 256
#define CPW   8                    // chunks per wave (half a row)
#define GRID_A (NROWS * CPR / CPW * 64 / BLOCK)   // 2048 blocks

// ws layout: float plane q of chunk c at ws[(c*5+q)*NROWS + row], q=0..4
// (A_c, B_c, s0, s1, s2). Planes: 80 * 4096 floats = 1.31 MB.
// Row partials (double[4096]) live after the planes.
#define WS_PLANES (CPR * 5)

__global__ __launch_bounds__(BLOCK) void retrace_stream(
    const float* __restrict__ Q,
    const float* __restrict__ eQ,
    const float* __restrict__ tQ,
    const float* __restrict__ rw,
    const float* __restrict__ tpp,
    const float* __restrict__ bpp,
    float* __restrict__ ws)
{
    constexpr float G = 0.99f;
    const int lane = threadIdx.x & 63;
    const int wid  = blockIdx.x * (BLOCK / 64) + (threadIdx.x >> 6);
    const int row  = wid >> 1;
    const int c0   = (wid & 1) * CPW;          // this wave's first chunk
    const long long base = (long long)row * TLEN;

    // ---- load chunk c0 (current buffer): 6 float4 + 4 boundary scalars ----
    long long off = base + (long long)c0 * CHUNK + 4 * lane;
    float4 cR  = *(const float4*)(rw  + off);
    float4 cT  = *(const float4*)(tpp + off);
    float4 cP  = *(const float4*)(bpp + off);
    float4 cQt = *(const float4*)(tQ  + off);
    float4 cE  = *(const float4*)(eQ  + off);
    float4 cQm = *(const float4*)(Q   + off);
    float cbT = 0.f, cbP = 0.f, cbQ = 0.f, cbE = 0.f;
    {
        const int tn = c0 * CHUNK + CHUNK;     // first element of chunk above
        if (tn < TLEN) {                        // wave-uniform branch
            cbT = tpp[base + tn]; cbP = bpp[base + tn];
            cbQ = tQ [base + tn]; cbE = eQ [base + tn];
        }
    }

    #pragma unroll 1
    for (int k = 0; k < CPW; ++k) {
        const int c = c0 + k;

        // ---- prefetch next chunk before touching current data ----
        float4 nR, nT, nP, nQt, nE, nQm;
        float nbT = 0.f, nbP = 0.f, nbQ = 0.f, nbE = 0.f;
        if (k + 1 < CPW) {
            const long long noff = base + (long long)(c + 1) * CHUNK + 4 * lane;
            nR  = *(const float4*)(rw  + noff);
            nT  = *(const float4*)(tpp + noff);
            nP  = *(const float4*)(bpp + noff);
            nQt = *(const float4*)(tQ  + noff);
            nE  = *(const float4*)(eQ  + noff);
            nQm = *(const float4*)(Q   + noff);
            const int tn = (c + 1) * CHUNK + CHUNK;
            if (tn < TLEN) {
                nbT = tpp[base + tn]; nbP = bpp[base + tn];
                nbQ = tQ [base + tn]; nbE = eQ [base + tn];
            }
        }

        // ---- shifted (t+1) values for this lane's top element ----
        float t3 = __shfl_down(cT.x,  1, 64);
        float p3 = __shfl_down(cP.x,  1, 64);
        float q3 = __shfl_down(cQt.x, 1, 64);
        float e3 = __shfl_down(cE.x,  1, 64);
        const bool top = (lane == 63);
        if (top) { t3 = cbT; p3 = cbP; q3 = cbQ; e3 = cbE; }

        const float rv[4] = {cR.x,  cR.y,  cR.z,  cR.w};
        const float tv[4] = {cT.x,  cT.y,  cT.z,  cT.w};
        const float pv[4] = {cP.x,  cP.y,  cP.z,  cP.w};
        const float qv[4] = {cQt.x, cQt.y, cQt.z, cQt.w};
        const float ev[4] = {cE.x,  cE.y,  cE.z,  cE.w};
        const float qm[4] = {cQm.x, cQm.y, cQm.z, cQm.w};

        // ---- build maps m_j for t_j = 256c + 4*lane + j ----
        // m.A = G*exp(min(tpp[t+1]-bpp[t+1],0));
        // m.B = 100*r[t] + G*eq[t+1] - m.A*tq[t+1]
        float A[4], B[4];
        #pragma unroll
        for (int j = 0; j < 3; ++j) {
            const float cr = __expf(fminf(tv[j+1] - pv[j+1], 0.0f));
            const float gc = G * cr;
            A[j] = gc;
            B[j] = fmaf(100.0f, rv[j], fmaf(-gc, qv[j+1], G * ev[j+1]));
        }
        if (top && c == CPR - 1) {
            // t = 4095 anchor: y = tQ[4095] exactly.
            A[3] = 0.0f;
            B[3] = qv[3];
        } else {
            const float cr = __expf(fminf(t3 - p3, 0.0f));
            const float gc = G * cr;
            A[3] = gc;
            B[3] = fmaf(100.0f, rv[3], fmaf(-gc, q3, G * e3));
        }

        // ---- lane-local inclusive-from-top composites (j..3) ----
        // compose(m, n) = apply n (above) then m: (m.A*n.A, m.A*n.B + m.B)
        float CA[4], CB[4];
        CA[3] = A[3];            CB[3] = B[3];
        CA[2] = A[2] * CA[3];    CB[2] = fmaf(A[2], CB[3], B[2]);
        CA[1] = A[1] * CA[2];    CB[1] = fmaf(A[1], CB[2], B[1]);
        CA[0] = A[0] * CA[1];    CB[0] = fmaf(A[0], CB[1], B[0]);

        // ---- wave suffix scan (Kogge-Stone, from high lanes down) ----
        float SA = CA[0], SB = CB[0];
        #pragma unroll
        for (int o = 1; o < 64; o <<= 1) {
            const float nA = __shfl_down(SA, o, 64);
            const float nB = __shfl_down(SB, o, 64);
            if (lane + o < 64) {
                SB = fmaf(SA, nB, SB);
                SA = SA * nA;
            }
        }
        // exclusive suffix for this lane = inclusive of lane+1
        float EA = __shfl_down(SA, 1, 64);
        float EB = __shfl_down(SB, 1, 64);
        if (top) { EA = 1.0f; EB = 0.0f; }

        // ---- per-element full composites + loss moments ----
        float s0 = 0.f, s1 = 0.f, s2 = 0.f;
        #pragma unroll
        for (int j = 0; j < 4; ++j) {
            const float cA = CA[j] * EA;
            const float cB = fmaf(CA[j], EB, CB[j]);
            const float P  = qm[j] - cB;
            s0 = fmaf(cA, cA, s0);
            s1 = fmaf(P,  cA, s1);
            s2 = fmaf(P,  P,  s2);
        }
        // wave reduction of the three moments
        #pragma unroll
        for (int o = 32; o > 0; o >>= 1) {
            s0 += __shfl_down(s0, o, 64);
            s1 += __shfl_down(s1, o, 64);
            s2 += __shfl_down(s2, o, 64);
        }

        if (lane == 0) {
            float* w = ws + (size_t)(c * 5) * NROWS + row;
            w[0 * NROWS] = SA;   // chunk composite A (lane 0 inclusive = full)
            w[1 * NROWS] = SB;   // chunk composite B
            w[2 * NROWS] = s0;
            w[3 * NROWS] = s1;
            w[4 * NROWS] = s2;
        }

        // ---- rotate buffers ----
        cR = nR; cT = nT; cP = nP; cQt = nQt; cE = nE; cQm = nQm;
        cbT = nbT; cbP = nbP; cbQ = nbQ; cbE = nbE;
    }
}

// One thread per row: resolve the 16-chunk recurrence, emit per-row loss.
__global__ __launch_bounds__(BLOCK) void retrace_resolve(
    const float* __restrict__ ws, double* __restrict__ partials)
{
    const int row = blockIdx.x * BLOCK + threadIdx.x;
    float y = 0.0f;                    // chunk 15 has all C.A == 0 -> y_in moot
    double loss = 0.0;
    #pragma unroll
    for (int c = CPR - 1; c >= 0; --c) {
        const float* w = ws + (size_t)(c * 5) * NROWS + row;
        const float Ac = w[0 * NROWS];
        const float Bc = w[1 * NROWS];
        const float s0 = w[2 * NROWS];
        const float s1 = w[3 * NROWS];
        const float s2 = w[4 * NROWS];
        loss += (double)fmaf(fmaf(s0, y, -2.0f * s1), y, s2);
        y = fmaf(Ac, y, Bc);
    }
    partials[row] = loss;
}

__global__ __launch_bounds__(256) void retrace_finalize(
    const double* __restrict__ partials, float* __restrict__ out)
{
    __shared__ double sRed[4];
    double s = 0.0;
    for (int i = threadIdx.x; i < NROWS; i += 256) s += partials[i];
    #pragma unroll
    for (int off = 32; off > 0; off >>= 1)
        s += __shfl_down(s, off, 64);
    if ((threadIdx.x & 63) == 0) sRed[threadIdx.x >> 6] = s;
    __syncthreads();
    if (threadIdx.x == 0) {
        const double tot = sRed[0] + sRed[1] + sRed[2] + sRed[3];
        out[0] = (float)(tot / ((double)NROWS * (double)TLEN));
    }
}

extern "C" void kernel_launch(void* const* d_in, const int* in_sizes, int n_in,
                              void* d_out, int out_size, void* d_ws, size_t ws_size,
                              hipStream_t stream)
{
    // setup_inputs order: Q, expected_target_Q, target_Q, rewards,
    //                     target_policy_probs, behaviour_policy_probs
    const float* Q   = (const float*)d_in[0];
    const float* eQ  = (const float*)d_in[1];
    const float* tQ  = (const float*)d_in[2];
    const float* rw  = (const float*)d_in[3];
    const float* tpp = (const float*)d_in[4];
    const float* bpp = (const float*)d_in[5];

    float*  ws       = (float*)d_ws;                       // 80*4096 floats = 1.31 MB
    double* partials = (double*)(ws + (size_t)WS_PLANES * NROWS);  // 8B-aligned

    retrace_stream<<<GRID_A, BLOCK, 0, stream>>>(Q, eQ, tQ, rw, tpp, bpp, ws);
    retrace_resolve<<<NROWS / BLOCK, BLOCK, 0, stream>>>(ws, partials);
    retrace_finalize<<<1, 256, 0, stream>>>(partials, (float*)d_out);
}